// Round 12
// baseline (140.244 us; speedup 1.0000x reference)
//
#include <hip/hip_runtime.h>
#include <stdint.h>

#define IN_F   512
#define N_CTR  2048
#define BATCH  16384
#define BK     64
#define NKT    (IN_F / BK)   // 8

#define BM 256   // rows per block = 8 waves x 32
#define BN 64    // cols per block = B-tile rows
#define KH 256   // K elements per staged half (32 KB)

using bf16x8  = __attribute__((ext_vector_type(8))) short;
using f32x4   = __attribute__((ext_vector_type(4))) float;
using ushort8 = __attribute__((ext_vector_type(8))) unsigned short;

typedef const __attribute__((address_space(1))) void* gptr_t;
typedef __attribute__((address_space(3))) void* lptr_t;

static __device__ __forceinline__ unsigned short f2bf(float f) {
    uint32_t u = __builtin_bit_cast(uint32_t, f);
    uint32_t r = u + 0x7fffu + ((u >> 16) & 1u);   // RNE
    return (unsigned short)(r >> 16);
}

// Merged converter (proven R1): one wave per row across BOTH x and centers.
__global__ void convert_all(const float* __restrict__ x,
                            const float* __restrict__ c,
                            unsigned short* __restrict__ xb,
                            unsigned short* __restrict__ cb,
                            float* __restrict__ xsq,
                            float* __restrict__ csq) {
    const int wave = threadIdx.x >> 6;
    const int lane = threadIdx.x & 63;
    const int row  = blockIdx.x * 4 + wave;

    const float* src;
    unsigned short* dst;
    float* sq;
    int r;
    if (row < BATCH) { src = x; dst = xb; sq = xsq; r = row; }
    else             { src = c; dst = cb; sq = csq; r = row - BATCH; }

    const float* rp = src + (size_t)r * IN_F + lane * 8;
    float4 a = *reinterpret_cast<const float4*>(rp);
    float4 b = *reinterpret_cast<const float4*>(rp + 4);
    float ss = a.x*a.x + a.y*a.y + a.z*a.z + a.w*a.w
             + b.x*b.x + b.y*b.y + b.z*b.z + b.w*b.w;
    ushort8 o;
    o[0]=f2bf(a.x); o[1]=f2bf(a.y); o[2]=f2bf(a.z); o[3]=f2bf(a.w);
    o[4]=f2bf(b.x); o[5]=f2bf(b.y); o[6]=f2bf(b.z); o[7]=f2bf(b.w);
    *reinterpret_cast<ushort8*>(dst + (size_t)r * IN_F + lane * 8) = o;
    #pragma unroll
    for (int off = 32; off > 0; off >>= 1) ss += __shfl_down(ss, off);
    if (lane == 0) sq[r] = ss;
}

// B-stationary / A-streaming RBF GEMM, split-K B staging for occupancy:
//  - B tile staged in TWO 32 KB K-halves (Bs[64][256]) -> LDS 32 KB ->
//    4 blocks/CU = 32 waves/CU (R11 was 64 KB -> 2 blocks -> latency-bound
//    at 37% occupancy with every pipe < 40%).
//  - launch_bounds(512,8): 64-VGPR cap; R11 measured live set = 52, fits.
//  - 3 barriers total; A streams global->reg, unroll-2 static dbuf (rule 20).
__launch_bounds__(512, 8)
__global__ void rbf_gemm_stream(const unsigned short* __restrict__ xb,
                                const unsigned short* __restrict__ cb,
                                const float* __restrict__ xsq,
                                const float* __restrict__ csq,
                                const float* __restrict__ beta,
                                float* __restrict__ out) {
    __shared__ __align__(16) unsigned short Bs[BN * KH];   // 32 KiB

    const int tid  = threadIdx.x;
    const int wid  = tid >> 6;          // 0..7
    const int lane = tid & 63;
    const int g16  = lane >> 4;         // 0..3
    const int l16  = lane & 15;

    // T1 XCD chunked swizzle (bijective: 2048 % 8 == 0). tn fastest.
    const int bid  = blockIdx.x;
    const int swzc = (bid & 7) * 256 + (bid >> 3);
    const int tm   = swzc >> 5;         // 0..63
    const int tn   = swzc & 31;         // 0..31

    // ---- B staging: one 32 KB half; row r linear, source chunk ^(r&7) ----
    // Each global_load_lds covers 2 rows (64 lanes x 16B = 1024 B = 2x512 B).
    auto stageB = [&](int half) {
        #pragma unroll
        for (int j = 0; j < 4; ++j) {
            const int r2    = wid * 8 + j * 2;          // wave-uniform
            const int row   = r2 + (lane >> 5);
            const int chunk = (lane & 31) ^ (row & 7);  // rule 21: pre-swz source
            const unsigned short* src =
                cb + (size_t)(tn * BN + row) * IN_F + half * KH + chunk * 8;
            __builtin_amdgcn_global_load_lds((gptr_t)src, (lptr_t)(Bs + r2 * KH), 16, 0, 0);
        }
    };

    const int arow0 = tm * BM + wid * 32;
    const unsigned short* gA = xb + (size_t)(arow0 + l16) * IN_F + g16 * 8;

    f32x4  acc[2][4] = {};
    bf16x8 afA[2][2], afB[2][2];

    auto loadA = [&](bf16x8 dst[2][2], int kt) {
        #pragma unroll
        for (int i = 0; i < 2; ++i)
            #pragma unroll
            for (int kk = 0; kk < 2; ++kk)
                dst[i][kk] = *reinterpret_cast<const bf16x8*>(
                    gA + (size_t)(i * 16) * IN_F + kt * BK + kk * 32);
    };

    auto computeKT = [&](bf16x8 af[2][2], int kt) {
        const int ktl = kt & 3;                          // K-tile within half
        #pragma unroll
        for (int kk = 0; kk < 2; ++kk) {
            bf16x8 bfr[4];
            #pragma unroll
            for (int ni = 0; ni < 4; ++ni) {
                const int rb   = ni * 16 + l16;          // B row 0..63
                const int slot = ktl * 8 + ((kk * 4 + g16) ^ (rb & 7));
                bfr[ni] = *reinterpret_cast<const bf16x8*>(
                    (const char*)Bs + rb * (KH * 2) + slot * 16);
            }
            #pragma unroll
            for (int i = 0; i < 2; ++i)
                #pragma unroll
                for (int ni = 0; ni < 4; ++ni)
                    acc[i][ni] = __builtin_amdgcn_mfma_f32_16x16x32_bf16(
                        af[i][kk], bfr[ni], acc[i][ni], 0, 0, 0);
        }
    };

    // ---- half 0 ----
    stageB(0);
    loadA(afA, 0);
    __syncthreads();                    // half0 staged (drains vmcnt)

    loadA(afB, 1);
    computeKT(afA, 0);
    loadA(afA, 2);
    computeKT(afB, 1);
    loadA(afB, 3);
    computeKT(afA, 2);
    loadA(afA, 4);                      // first K-tile of half 1 (A only)
    computeKT(afB, 3);

    __syncthreads();                    // all reads of half0 complete
    // ---- half 1 ----
    stageB(1);
    __syncthreads();                    // half1 staged

    loadA(afB, 5);
    computeKT(afA, 4);
    loadA(afA, 6);
    computeKT(afB, 5);
    loadA(afB, 7);
    computeKT(afA, 6);
    computeKT(afB, 7);

    // ---- epilogue: out = exp(-beta * (xsq + csq - 2*cross)) ----
    const int colb = tn * BN;
    float csb[4], btb[4];
    #pragma unroll
    for (int ni = 0; ni < 4; ++ni) {
        const int col = colb + ni * 16 + l16;
        csb[ni] = csq[col];
        btb[ni] = beta[col];
    }
    #pragma unroll
    for (int i = 0; i < 2; ++i) {
        #pragma unroll
        for (int j = 0; j < 4; ++j) {
            const int row = arow0 + i * 16 + g16 * 4 + j;   // C/D: row=(lane>>4)*4+reg
            const float xs = xsq[row];
            float* op = out + (size_t)row * N_CTR + colb;
            #pragma unroll
            for (int ni = 0; ni < 4; ++ni)
                op[ni * 16 + l16] = __expf(-btb[ni] * (xs + csb[ni] - 2.0f * acc[i][ni][j]));
        }
    }
}

// Fallback (ws too small): correct f32 path, LDS-staged x row.
__global__ void rbf_naive(const float* __restrict__ x,
                          const float* __restrict__ c,
                          const float* __restrict__ beta,
                          float* __restrict__ out) {
    __shared__ float xs[IN_F];
    const int row = blockIdx.x;
    const int col = blockIdx.y * 128 + threadIdx.x;
    for (int i = threadIdx.x; i < IN_F; i += 128)
        xs[i] = x[(size_t)row * IN_F + i];
    __syncthreads();
    const float* cp = c + (size_t)col * IN_F;
    float d = 0.f;
    #pragma unroll 4
    for (int k = 0; k < IN_F; k += 4) {
        float4 cv = *reinterpret_cast<const float4*>(cp + k);
        float t0 = xs[k + 0] - cv.x;
        float t1 = xs[k + 1] - cv.y;
        float t2 = xs[k + 2] - cv.z;
        float t3 = xs[k + 3] - cv.w;
        d += t0 * t0 + t1 * t1 + t2 * t2 + t3 * t3;
    }
    out[(size_t)row * N_CTR + col] = __expf(-beta[col] * d);
}

extern "C" void kernel_launch(void* const* d_in, const int* in_sizes, int n_in,
                              void* d_out, int out_size, void* d_ws, size_t ws_size,
                              hipStream_t stream) {
    const float* x    = (const float*)d_in[0];
    const float* c    = (const float*)d_in[1];
    const float* beta = (const float*)d_in[2];
    float* out        = (float*)d_out;

    const size_t need = (size_t)BATCH * IN_F * 2 + (size_t)N_CTR * IN_F * 2
                      + (size_t)BATCH * 4 + (size_t)N_CTR * 4;
    if (ws_size >= need) {
        unsigned short* xbuf = (unsigned short*)d_ws;
        unsigned short* cbuf = xbuf + (size_t)BATCH * IN_F;
        float* xsq = (float*)(cbuf + (size_t)N_CTR * IN_F);
        float* csq = xsq + BATCH;
        convert_all<<<(BATCH + N_CTR) / 4, 256, 0, stream>>>(x, c, xbuf, cbuf, xsq, csq);
        rbf_gemm_stream<<<(BATCH / BM) * (N_CTR / BN), 512, 0, stream>>>(
            xbuf, cbuf, xsq, csq, beta, out);
    } else {
        rbf_naive<<<dim3(BATCH, N_CTR / 128), 128, 0, stream>>>(x, c, beta, out);
    }
}

// Round 13
// 91.602 us; speedup vs baseline: 1.5310x; 1.5310x over previous
//
#include <hip/hip_runtime.h>
#include <stdint.h>

#define IN_F   512
#define N_CTR  2048
#define BATCH  16384
#define BK     64
#define NKT    (IN_F / BK)   // 8

#define BM 256   // rows per block = 8 waves x 32
#define BN 64    // cols per block = B-tile rows
#define KH 256   // K elements per staged half (32 KB)

using bf16x8  = __attribute__((ext_vector_type(8))) short;
using f32x4   = __attribute__((ext_vector_type(4))) float;
using ushort8 = __attribute__((ext_vector_type(8))) unsigned short;

typedef const __attribute__((address_space(1))) void* gptr_t;
typedef __attribute__((address_space(3))) void* lptr_t;

static __device__ __forceinline__ unsigned short f2bf(float f) {
    uint32_t u = __builtin_bit_cast(uint32_t, f);
    uint32_t r = u + 0x7fffu + ((u >> 16) & 1u);   // RNE
    return (unsigned short)(r >> 16);
}

// Merged converter (proven R1): one wave per row across BOTH x and centers.
__global__ void convert_all(const float* __restrict__ x,
                            const float* __restrict__ c,
                            unsigned short* __restrict__ xb,
                            unsigned short* __restrict__ cb,
                            float* __restrict__ xsq,
                            float* __restrict__ csq) {
    const int wave = threadIdx.x >> 6;
    const int lane = threadIdx.x & 63;
    const int row  = blockIdx.x * 4 + wave;

    const float* src;
    unsigned short* dst;
    float* sq;
    int r;
    if (row < BATCH) { src = x; dst = xb; sq = xsq; r = row; }
    else             { src = c; dst = cb; sq = csq; r = row - BATCH; }

    const float* rp = src + (size_t)r * IN_F + lane * 8;
    float4 a = *reinterpret_cast<const float4*>(rp);
    float4 b = *reinterpret_cast<const float4*>(rp + 4);
    float ss = a.x*a.x + a.y*a.y + a.z*a.z + a.w*a.w
             + b.x*b.x + b.y*b.y + b.z*b.z + b.w*b.w;
    ushort8 o;
    o[0]=f2bf(a.x); o[1]=f2bf(a.y); o[2]=f2bf(a.z); o[3]=f2bf(a.w);
    o[4]=f2bf(b.x); o[5]=f2bf(b.y); o[6]=f2bf(b.z); o[7]=f2bf(b.w);
    *reinterpret_cast<ushort8*>(dst + (size_t)r * IN_F + lane * 8) = o;
    #pragma unroll
    for (int off = 32; off > 0; off >>= 1) ss += __shfl_down(ss, off);
    if (lane == 0) sq[r] = ss;
}

// B-stationary / A-streaming RBF GEMM, split-K B staging (32 KB LDS ->
// 4 blocks/CU). R12 lesson: NEVER set the launch_bounds min-occupancy arg —
// (512,8) forced a 32-VGPR cap and 380 MB of spill; with no arg the
// allocator targets the LDS-implied 8 waves/SIMD => 64-VGPR budget, which
// the measured 52-reg live set fits spill-free (R11: VGPR_Count=52).
__launch_bounds__(512)
__global__ void rbf_gemm_stream(const unsigned short* __restrict__ xb,
                                const unsigned short* __restrict__ cb,
                                const float* __restrict__ xsq,
                                const float* __restrict__ csq,
                                const float* __restrict__ beta,
                                float* __restrict__ out) {
    __shared__ __align__(16) unsigned short Bs[BN * KH];   // 32 KiB

    const int tid  = threadIdx.x;
    const int wid  = tid >> 6;          // 0..7
    const int lane = tid & 63;
    const int g16  = lane >> 4;         // 0..3
    const int l16  = lane & 15;

    // T1 XCD chunked swizzle (bijective: 2048 % 8 == 0). tn fastest.
    const int bid  = blockIdx.x;
    const int swzc = (bid & 7) * 256 + (bid >> 3);
    const int tm   = swzc >> 5;         // 0..63
    const int tn   = swzc & 31;         // 0..31

    // ---- B staging: one 32 KB half; row r linear, source chunk ^(r&7) ----
    // Each global_load_lds covers 2 rows (64 lanes x 16B = 1024 B = 2x512 B).
    auto stageB = [&](int half) {
        #pragma unroll
        for (int j = 0; j < 4; ++j) {
            const int r2    = wid * 8 + j * 2;          // wave-uniform
            const int row   = r2 + (lane >> 5);
            const int chunk = (lane & 31) ^ (row & 7);  // rule 21: pre-swz source
            const unsigned short* src =
                cb + (size_t)(tn * BN + row) * IN_F + half * KH + chunk * 8;
            __builtin_amdgcn_global_load_lds((gptr_t)src, (lptr_t)(Bs + r2 * KH), 16, 0, 0);
        }
    };

    const int arow0 = tm * BM + wid * 32;
    const unsigned short* gA = xb + (size_t)(arow0 + l16) * IN_F + g16 * 8;

    f32x4  acc[2][4] = {};
    bf16x8 afA[2][2], afB[2][2];

    auto loadA = [&](bf16x8 dst[2][2], int kt) {
        #pragma unroll
        for (int i = 0; i < 2; ++i)
            #pragma unroll
            for (int kk = 0; kk < 2; ++kk)
                dst[i][kk] = *reinterpret_cast<const bf16x8*>(
                    gA + (size_t)(i * 16) * IN_F + kt * BK + kk * 32);
    };

    auto computeKT = [&](bf16x8 af[2][2], int kt) {
        const int ktl = kt & 3;                          // K-tile within half
        #pragma unroll
        for (int kk = 0; kk < 2; ++kk) {
            bf16x8 bfr[4];
            #pragma unroll
            for (int ni = 0; ni < 4; ++ni) {
                const int rb   = ni * 16 + l16;          // B row 0..63
                const int slot = ktl * 8 + ((kk * 4 + g16) ^ (rb & 7));
                bfr[ni] = *reinterpret_cast<const bf16x8*>(
                    (const char*)Bs + rb * (KH * 2) + slot * 16);
            }
            #pragma unroll
            for (int i = 0; i < 2; ++i)
                #pragma unroll
                for (int ni = 0; ni < 4; ++ni)
                    acc[i][ni] = __builtin_amdgcn_mfma_f32_16x16x32_bf16(
                        af[i][kk], bfr[ni], acc[i][ni], 0, 0, 0);
        }
    };

    // ---- half 0 ----
    stageB(0);
    loadA(afA, 0);
    __syncthreads();                    // half0 staged (drains vmcnt)

    loadA(afB, 1);
    computeKT(afA, 0);
    loadA(afA, 2);
    computeKT(afB, 1);
    loadA(afB, 3);
    computeKT(afA, 2);
    loadA(afA, 4);                      // first K-tile of half 1 (A only)
    computeKT(afB, 3);

    __syncthreads();                    // all reads of half0 complete
    // ---- half 1 ----
    stageB(1);
    __syncthreads();                    // half1 staged

    loadA(afB, 5);
    computeKT(afA, 4);
    loadA(afA, 6);
    computeKT(afB, 5);
    loadA(afB, 7);
    computeKT(afA, 6);
    computeKT(afB, 7);

    // ---- epilogue: out = exp(-beta * (xsq + csq - 2*cross)) ----
    const int colb = tn * BN;
    float csb[4], btb[4];
    #pragma unroll
    for (int ni = 0; ni < 4; ++ni) {
        const int col = colb + ni * 16 + l16;
        csb[ni] = csq[col];
        btb[ni] = beta[col];
    }
    #pragma unroll
    for (int i = 0; i < 2; ++i) {
        #pragma unroll
        for (int j = 0; j < 4; ++j) {
            const int row = arow0 + i * 16 + g16 * 4 + j;   // C/D: row=(lane>>4)*4+reg
            const float xs = xsq[row];
            float* op = out + (size_t)row * N_CTR + colb;
            #pragma unroll
            for (int ni = 0; ni < 4; ++ni)
                op[ni * 16 + l16] = __expf(-btb[ni] * (xs + csb[ni] - 2.0f * acc[i][ni][j]));
        }
    }
}

// Fallback (ws too small): correct f32 path, LDS-staged x row.
__global__ void rbf_naive(const float* __restrict__ x,
                          const float* __restrict__ c,
                          const float* __restrict__ beta,
                          float* __restrict__ out) {
    __shared__ float xs[IN_F];
    const int row = blockIdx.x;
    const int col = blockIdx.y * 128 + threadIdx.x;
    for (int i = threadIdx.x; i < IN_F; i += 128)
        xs[i] = x[(size_t)row * IN_F + i];
    __syncthreads();
    const float* cp = c + (size_t)col * IN_F;
    float d = 0.f;
    #pragma unroll 4
    for (int k = 0; k < IN_F; k += 4) {
        float4 cv = *reinterpret_cast<const float4*>(cp + k);
        float t0 = xs[k + 0] - cv.x;
        float t1 = xs[k + 1] - cv.y;
        float t2 = xs[k + 2] - cv.z;
        float t3 = xs[k + 3] - cv.w;
        d += t0 * t0 + t1 * t1 + t2 * t2 + t3 * t3;
    }
    out[(size_t)row * N_CTR + col] = __expf(-beta[col] * d);
}

extern "C" void kernel_launch(void* const* d_in, const int* in_sizes, int n_in,
                              void* d_out, int out_size, void* d_ws, size_t ws_size,
                              hipStream_t stream) {
    const float* x    = (const float*)d_in[0];
    const float* c    = (const float*)d_in[1];
    const float* beta = (const float*)d_in[2];
    float* out        = (float*)d_out;

    const size_t need = (size_t)BATCH * IN_F * 2 + (size_t)N_CTR * IN_F * 2
                      + (size_t)BATCH * 4 + (size_t)N_CTR * 4;
    if (ws_size >= need) {
        unsigned short* xbuf = (unsigned short*)d_ws;
        unsigned short* cbuf = xbuf + (size_t)BATCH * IN_F;
        float* xsq = (float*)(cbuf + (size_t)N_CTR * IN_F);
        float* csq = xsq + BATCH;
        convert_all<<<(BATCH + N_CTR) / 4, 256, 0, stream>>>(x, c, xbuf, cbuf, xsq, csq);
        rbf_gemm_stream<<<(BATCH / BM) * (N_CTR / BN), 512, 0, stream>>>(
            xbuf, cbuf, xsq, csq, beta, out);
    } else {
        rbf_naive<<<dim3(BATCH, N_CTR / 128), 128, 0, stream>>>(x, c, beta, out);
    }
}